// Round 8
// baseline (288.010 us; speedup 1.0000x reference)
//
#include <hip/hip_runtime.h>
#include <hip/hip_bf16.h>

typedef __bf16 b16;
typedef __bf16 b16x4 __attribute__((ext_vector_type(4)));
typedef __bf16 b16x8 __attribute__((ext_vector_type(8)));
typedef float  f32x4 __attribute__((ext_vector_type(4)));

#define B_   64
#define N_   196
#define C_   768
#define H_   12
#define HD_  64
#define TOK  (B_*N_)      // 12544
#define SCALE 0.125f

// ---------------------------------------------------------------- transpose+cvt
__global__ __launch_bounds__(256) void k_transpose_cvt(const float* __restrict__ in,
                                                       b16* __restrict__ out, int R, int C){
  __shared__ b16 tile[32][33];
  int tx = threadIdx.x, ty = threadIdx.y;
  int bx = blockIdx.x, by = blockIdx.y;
  int c = bx*32 + tx;
  #pragma unroll
  for (int i = 0; i < 32; i += 8){
    int r = by*32 + ty + i;
    tile[ty+i][tx] = (b16)in[(long)r*C + c];
  }
  __syncthreads();
  int rr = by*32 + tx;
  #pragma unroll
  for (int i = 0; i < 32; i += 8){
    int cc = bx*32 + ty + i;
    out[(long)cc*R + rr] = tile[tx][ty+i];
  }
}

// ---------------------------------------------------------------- x f32 -> bf16
__global__ __launch_bounds__(256) void k_cvt(const float* __restrict__ in, b16* __restrict__ out){
  long i = ((long)blockIdx.x*256 + threadIdx.x)*8;
  const float4* s = (const float4*)(in + i);
  float4 f0 = s[0], f1 = s[1];
  b16x8 v; v[0]=(b16)f0.x; v[1]=(b16)f0.y; v[2]=(b16)f0.z; v[3]=(b16)f0.w;
           v[4]=(b16)f1.x; v[5]=(b16)f1.y; v[6]=(b16)f1.z; v[7]=(b16)f1.w;
  *(b16x8*)(out + i) = v;
}

// ---------------------------------------------------------------- K = k^T k, ksum (4 blocks)
__global__ __launch_bounds__(256) void k_kprep(const float* __restrict__ k_ext,
                                               float* __restrict__ Kmat, float* __restrict__ ksum){
  __shared__ float ks[N_][HD_];
  int tid = threadIdx.x, blk = blockIdx.x;       // blk 0..3
  for (int i = tid; i < N_*HD_; i += 256) ks[i/HD_][i%HD_] = k_ext[i];
  __syncthreads();
  int i = tid >> 2;
  int j0 = blk*16 + (tid & 3)*4;
  float a0=0.f, a1=0.f, a2=0.f, a3=0.f;
  for (int p = 0; p < N_; ++p){
    float ki = ks[p][i];
    float4 kv = *(const float4*)&ks[p][j0];
    a0 += ki*kv.x; a1 += ki*kv.y; a2 += ki*kv.z; a3 += ki*kv.w;
  }
  Kmat[i*64+j0+0]=a0; Kmat[i*64+j0+1]=a1; Kmat[i*64+j0+2]=a2; Kmat[i*64+j0+3]=a3;
  if (blk == 0 && tid < 64){
    float s = 0.f;
    for (int p = 0; p < N_; ++p) s += ks[p][tid];
    ksum[tid] = s;
  }
}

// ---------------------------------------------------------------- no-LDS, zero-barrier MFMA GEMM
// Each wave owns an independent 64x64 output tile; A/B fragments loaded DIRECTLY from
// global in MFMA-native layout (16B/lane). No LDS, no barriers, no vmcnt choreography --
// compiler software-pipelines the 8 loads/K-step; latency hidden by TLP (VGPR-bound occupancy).
// B (weights) is L2-resident (2.3 MB); A streamed once. Swapped-operand MFMA keeps the
// vectorized epilogue (row=lane&15, col=(lane>>4)*4+j), verified round 7.
// MODE0: q/v bf16 [b,n,h,d] rows + fused BN stats; MODE1: f32 out + bias
template<int MODE>
__global__ __launch_bounds__(256) void k_gemm(const b16* __restrict__ A,
                                              const b16* __restrict__ BT,
                                              b16* __restrict__ qout, b16* __restrict__ vout,
                                              float* __restrict__ fout, const float* __restrict__ bias,
                                              const float* __restrict__ ksum, float* __restrict__ stats){
  const int NT  = (MODE == 0) ? 12 : 6;
  const int NWG = 98*NT;
  // bijective XCD swizzle (m204): 12 consecutive bids share the A-panel on one XCD
  int orig = blockIdx.x;
  int q8 = NWG >> 3, r8 = NWG & 7;
  int xcd = orig & 7, loc = orig >> 3;
  int bid = (xcd < r8 ? xcd*(q8+1) : r8*(q8+1) + (xcd-r8)*q8) + loc;
  int rt = bid / NT, ct = bid % NT;

  int tid = threadIdx.x, lane = tid & 63, w = tid >> 6;
  int wr = w >> 1, wc = w & 1;
  int brow = rt*128 + wr*64;            // per-wave 64x64 tile
  int bcol = ct*128 + wc*64;

  // fragment base pointers (MFMA A/B operand layout: lane holds [row=l&15][k=(l>>4)*8 ..+7])
  const b16* pa = A  + (long)(brow + (lane & 15))*768 + ((lane >> 4) << 3);
  const b16* pb = BT + (long)(bcol + (lane & 15))*768 + ((lane >> 4) << 3);

  f32x4 acc[4][4];
  #pragma unroll
  for (int m = 0; m < 4; ++m)
    #pragma unroll
    for (int n = 0; n < 4; ++n) acc[m][n] = (f32x4){0.f,0.f,0.f,0.f};

  #pragma unroll 4
  for (int kt = 0; kt < 24; ++kt){
    b16x8 af[4], bf[4];
    #pragma unroll
    for (int m = 0; m < 4; ++m) af[m] = *(const b16x8*)(pa + (long)m*16*768 + kt*32);
    #pragma unroll
    for (int n = 0; n < 4; ++n) bf[n] = *(const b16x8*)(pb + (long)n*16*768 + kt*32);
    #pragma unroll
    for (int m = 0; m < 4; ++m)
      #pragma unroll
      for (int n = 0; n < 4; ++n)
        acc[m][n] = __builtin_amdgcn_mfma_f32_16x16x32_bf16(bf[n], af[m], acc[m][n], 0, 0, 0);
  }

  // epilogue: row = brow + m*16 + (lane&15); col = bcol + n*16 + (lane>>4)*4 + j
  if constexpr (MODE == 0){
    bool isV = (bcol >= 768);
    b16* dst = isV ? vout : qout;
    int cb0 = bcol - (isV ? 768 : 0);
    #pragma unroll
    for (int m = 0; m < 4; ++m){
      int r2 = brow + m*16 + (lane & 15);
      #pragma unroll
      for (int n = 0; n < 4; ++n){
        int cc = cb0 + n*16 + ((lane>>4)<<2);
        b16x4 pv;
        #pragma unroll
        for (int j = 0; j < 4; ++j) pv[j] = (b16)acc[m][n][j];
        *(b16x4*)(dst + (long)r2*768 + cc) = pv;
      }
    }
    // fused BN stats (wave owns exactly ONE head: cols bcol..bcol+63)
    {
      float a_acc = 0.f, b_acc = 0.f;
      #pragma unroll
      for (int n = 0; n < 4; ++n)
        #pragma unroll
        for (int j = 0; j < 4; ++j){
          int d = n*16 + ((lane>>4)<<2) + j;        // col within head
          float s = 0.f, s2 = 0.f;
          #pragma unroll
          for (int m = 0; m < 4; ++m){
            float v = acc[m][n][j];
            s += v; s2 += v*v;
          }
          if (isV){ a_acc += s; b_acc += s2; }
          else      a_acc += s * ksum[d];
        }
      #pragma unroll
      for (int off = 1; off < 64; off <<= 1){
        a_acc += __shfl_xor(a_acc, off, 64);
        b_acc += __shfl_xor(b_acc, off, 64);
      }
      if (lane == 0){
        if (isV){
          int hv = 2*(ct - 6) + wc;
          atomicAdd(&stats[24 + hv], a_acc);
          atomicAdd(&stats[36 + hv], b_acc);
        } else {
          int hq = 2*ct + wc;
          atomicAdd(&stats[hq], a_acc);
        }
      }
    }
  } else {
    #pragma unroll
    for (int m = 0; m < 4; ++m){
      int r2 = brow + m*16 + (lane & 15);
      #pragma unroll
      for (int n = 0; n < 4; ++n){
        int cc = bcol + n*16 + ((lane>>4)<<2);
        f32x4 bv = *(const f32x4*)(bias + cc);
        f32x4 o;
        #pragma unroll
        for (int j = 0; j < 4; ++j) o[j] = acc[m][n][j] + bv[j];
        *(f32x4*)(fout + (long)r2*768 + cc) = o;
      }
    }
  }
}

// ---------------------------------------------------------------- per-head Gram G = sum_t q q^T (MFMA)
// q layout [b,n,h,d]: row stride 768
__global__ __launch_bounds__(256) void k_gram(const b16* __restrict__ qb, float* __restrict__ G){
  __shared__ b16 qT[64*232];          // [d][t] stride 232
  int tid = threadIdx.x, lane = tid & 63, w = tid >> 6;
  int h = blockIdx.x % 12, bg = blockIdx.x / 12;   // bg 0..31
  f32x4 acc[4];
  #pragma unroll
  for (int n = 0; n < 4; ++n) acc[n] = (f32x4){0.f,0.f,0.f,0.f};
  #pragma unroll 1
  for (int r = 0; r < 2; ++r){
    int b = bg*2 + r;
    const b16* src = qb + (long)(b*196)*768 + h*64;
    int d = lane;
    for (int p0 = w*8; p0 < 224; p0 += 32){
      b16x8 w8;
      #pragma unroll
      for (int j = 0; j < 8; ++j){
        int p = p0 + j;
        w8[j] = (p < 196) ? src[(long)p*768 + d] : (b16)0.f;
      }
      *(b16x8*)(qT + d*232 + p0) = w8;
    }
    __syncthreads();
    #pragma unroll
    for (int ks = 0; ks < 7; ++ks){
      int t0 = ks*32;
      b16x8 af = *(const b16x8*)(qT + (16*w + (lane&15))*232 + t0 + ((lane>>4)<<3));
      #pragma unroll
      for (int n = 0; n < 4; ++n){
        b16x8 bf = *(const b16x8*)(qT + (16*n + (lane&15))*232 + t0 + ((lane>>4)<<3));
        acc[n] = __builtin_amdgcn_mfma_f32_16x16x32_bf16(af, bf, acc[n], 0, 0, 0);
      }
    }
    __syncthreads();
  }
  float* Gh = G + h*4096;
  #pragma unroll
  for (int n = 0; n < 4; ++n)
    #pragma unroll
    for (int j = 0; j < 4; ++j){
      int i  = 16*w + ((lane>>4)<<2) + j;
      int jj = 16*n + (lane&15);
      atomicAdd(&Gh[i*64 + jj], acc[n][j]);
    }
}

// ---------------------------------------------------------------- S2 = <G,K>, finalize coefs
__global__ __launch_bounds__(256) void k_sfin(const float* __restrict__ G, const float* __restrict__ Kmat,
                                              const float* __restrict__ stats, const float* __restrict__ gamma,
                                              const float* __restrict__ beta, float* __restrict__ coef){
  int h = blockIdx.x, tid = threadIdx.x;
  const float* Gh = G + h*4096;
  float s = 0.f;
  #pragma unroll
  for (int k = 0; k < 16; ++k) s += Gh[tid + k*256]*Kmat[tid + k*256];
  #pragma unroll
  for (int off = 1; off < 64; off <<= 1) s += __shfl_xor(s, off, 64);
  __shared__ float red[4];
  if ((tid & 63) == 0) red[tid>>6] = s;
  __syncthreads();
  if (tid == 0){
    float S2 = red[0]+red[1]+red[2]+red[3];
    const float cntS = 2458624.f, cntV = 802816.f;
    float S1 = stats[h], VS = stats[24+h], VS2 = stats[36+h];
    float ms = S1/cntS;
    float vars = S2/cntS - ms*ms;
    float alpha = gamma[h]*SCALE*rsqrtf(vars + 1e-5f);
    float mv = VS/cntV;
    float varv = VS2/cntV - mv*mv;
    float a = gamma[h]*rsqrtf(varv + 1e-5f);
    coef[h*4+0] = alpha;
    coef[h*4+1] = a;
    coef[h*4+2] = beta[h] - a*mv;
  }
}

// ---------------------------------------------------------------- fused attention per (b,h)
// q/v layout [b,n,h,d]: row stride 768 elements (1536 B), head offset h*64
__global__ __launch_bounds__(256, 2) void k_attn(const b16* __restrict__ qb, const b16* __restrict__ vb,
                                                 const float* __restrict__ k_ext,
                                                 const float* __restrict__ attn_bias,
                                                 const float* __restrict__ coef,
                                                 b16* __restrict__ Ob){
  __shared__ b16 ksh[196*64];
  __shared__ b16 vsh[64*216];
  __shared__ b16 psh[4][16*200];
  __shared__ float bsh[196];

  int tid = threadIdx.x, lane = tid & 63, wid = tid >> 6;
  int bh = blockIdx.x;
  int h = bh % 12, b = bh / 12;
  const b16* qt = qb + (long)(b*196)*768 + h*64;
  const b16* vt = vb + (long)(b*196)*768 + h*64;
  float alpha = coef[h*4+0], av = coef[h*4+1], cv = coef[h*4+2];

  for (int c = tid; c < 196*8; c += 256){
    int p = c >> 3, g = c & 7;
    const float4* src = (const float4*)(k_ext + p*64 + g*8);
    float4 f0 = src[0], f1 = src[1];
    b16x8 v; v[0]=(b16)f0.x; v[1]=(b16)f0.y; v[2]=(b16)f0.z; v[3]=(b16)f0.w;
             v[4]=(b16)f1.x; v[5]=(b16)f1.y; v[6]=(b16)f1.z; v[7]=(b16)f1.w;
    *(b16x8*)((char*)ksh + p*128 + ((g ^ (p&7))<<4)) = v;
  }
  for (int p = tid; p < 196; p += 256) bsh[p] = attn_bias[p]*SCALE;
  {
    int d = tid & 63;
    for (int p0 = (tid>>6)*8; p0 < 196; p0 += 32){
      b16x8 w;
      #pragma unroll
      for (int j = 0; j < 8; ++j){
        int p = p0 + j;
        w[j] = (p < 196) ? vt[(long)p*768 + d] : (b16)0.f;
      }
      *(b16x8*)((char*)vsh + d*432 + p0*2) = w;
    }
  }
  __syncthreads();

  for (int rt = wid; rt < 13; rt += 4){
    int n0 = rt*16;
    int qrow = n0 + (lane & 15); if (qrow > 195) qrow = 195;
    b16x8 a0 = *(const b16x8*)((const char*)qt + (long)qrow*1536 +      ((lane>>4)<<4));
    b16x8 a1 = *(const b16x8*)((const char*)qt + (long)qrow*1536 + 64 + ((lane>>4)<<4));

    f32x4 sc[13];
    #pragma unroll
    for (int ct = 0; ct < 13; ++ct){
      int p = ct*16 + (lane & 15); int pc = p > 195 ? 195 : p;
      b16x8 b0 = *(const b16x8*)((const char*)ksh + pc*128 + ((( (lane>>4))   ^ (pc&7))<<4));
      b16x8 b1 = *(const b16x8*)((const char*)ksh + pc*128 + (((4+(lane>>4))  ^ (pc&7))<<4));
      f32x4 z = {0.f,0.f,0.f,0.f};
      z = __builtin_amdgcn_mfma_f32_16x16x32_bf16(a0, b0, z, 0, 0, 0);
      z = __builtin_amdgcn_mfma_f32_16x16x32_bf16(a1, b1, z, 0, 0, 0);
      sc[ct] = z;
    }
    int pcol = lane & 15;
    float mx[4] = {-1e30f,-1e30f,-1e30f,-1e30f};
    #pragma unroll
    for (int ct = 0; ct < 13; ++ct){
      int p = ct*16 + pcol;
      bool valid = (p < 196);
      float badd = valid ? bsh[p < 196 ? p : 0] : 0.f;
      #pragma unroll
      for (int j = 0; j < 4; ++j){
        float lv = valid ? (sc[ct][j]*alpha + badd) : -1e30f;
        sc[ct][j] = lv;
        mx[j] = fmaxf(mx[j], lv);
      }
    }
    #pragma unroll
    for (int off = 1; off < 16; off <<= 1)
      #pragma unroll
      for (int j = 0; j < 4; ++j) mx[j] = fmaxf(mx[j], __shfl_xor(mx[j], off, 64));
    float sm[4] = {0.f,0.f,0.f,0.f};
    #pragma unroll
    for (int ct = 0; ct < 13; ++ct)
      #pragma unroll
      for (int j = 0; j < 4; ++j){
        float e = __expf(sc[ct][j] - mx[j]);
        sc[ct][j] = e; sm[j] += e;
      }
    #pragma unroll
    for (int off = 1; off < 16; off <<= 1)
      #pragma unroll
      for (int j = 0; j < 4; ++j) sm[j] += __shfl_xor(sm[j], off, 64);
    float rs[4];
    #pragma unroll
    for (int j = 0; j < 4; ++j) rs[j] = 1.f/sm[j];

    b16* pw = psh[wid];
    #pragma unroll
    for (int ct = 0; ct < 12; ++ct){
      int p = ct*16 + pcol;
      #pragma unroll
      for (int j = 0; j < 4; ++j){
        int r = ((lane>>4)<<2) + j;
        pw[r*200 + p] = (b16)(sc[ct][j]*rs[j]);
      }
    }
    float pt12[4];
    #pragma unroll
    for (int j = 0; j < 4; ++j) pt12[j] = sc[12][j]*rs[j];

    __asm__ volatile("s_waitcnt lgkmcnt(0)" ::: "memory");
    __builtin_amdgcn_sched_barrier(0);

    f32x4 o[4];
    #pragma unroll
    for (int dt = 0; dt < 4; ++dt) o[dt] = (f32x4){0.f,0.f,0.f,0.f};
    #pragma unroll
    for (int pt = 0; pt < 6; ++pt){
      b16x8 pa = *(const b16x8*)((const char*)pw + (lane&15)*400 + pt*64 + ((lane>>4)<<4));
      #pragma unroll
      for (int dt = 0; dt < 4; ++dt){
        b16x8 vf = *(const b16x8*)((const char*)vsh + (dt*16 + (lane&15))*432 + pt*64 + ((lane>>4)<<4));
        o[dt] = __builtin_amdgcn_mfma_f32_16x16x32_bf16(pa, vf, o[dt], 0, 0, 0);
      }
    }
    #pragma unroll
    for (int e = 0; e < 4; ++e){
      float pe[4];
      #pragma unroll
      for (int j = 0; j < 4; ++j) pe[j] = __shfl(pt12[j], (lane & 48) + e, 64);
      #pragma unroll
      for (int dt = 0; dt < 4; ++dt){
        b16 vv = *((const b16*)((const char*)vsh + (dt*16 + (lane&15))*432 + (192+e)*2));
        float vvf = (float)vv;
        #pragma unroll
        for (int j = 0; j < 4; ++j) o[dt][j] += pe[j]*vvf;
      }
    }
    #pragma unroll
    for (int dt = 0; dt < 4; ++dt)
      #pragma unroll
      for (int j = 0; j < 4; ++j){
        int n = n0 + ((lane>>4)<<2) + j;
        if (n < 196){
          long idx = ((long)(b*196 + n))*768 + h*64 + dt*16 + (lane&15);
          Ob[idx] = (b16)(av*o[dt][j] + cv);
        }
      }
  }
}

// ---------------------------------------------------------------- launch
extern "C" void kernel_launch(void* const* d_in, const int* in_sizes, int n_in,
                              void* d_out, int out_size, void* d_ws, size_t ws_size,
                              hipStream_t stream){
  const float* x         = (const float*)d_in[0];
  const float* W_qv      = (const float*)d_in[1];
  const float* k_ext     = (const float*)d_in[2];
  const float* attn_bias = (const float*)d_in[3];
  const float* bn_gamma  = (const float*)d_in[4];
  const float* bn_beta   = (const float*)d_in[5];
  const float* W_proj    = (const float*)d_in[6];
  const float* b_proj    = (const float*)d_in[7];
  float* out = (float*)d_out;

  char* ws = (char*)d_ws;
  const long SZ = 19267584;              // 9,633,792 bf16
  b16*   q_buf   = (b16*)(ws);
  b16*   v_buf   = (b16*)(ws + SZ);
  b16*   O_buf   = (b16*)(ws + 2*SZ);    // doubles as x_bf16 before k_attn
  b16*   x_bf16  = (b16*)(ws + 2*SZ);
  b16*   W_qvT   = (b16*)(ws + 3*SZ);
  b16*   W_projT = (b16*)(ws + 3*SZ + 2359296);
  float* Kmat    = (float*)(ws + 3*SZ + 3538944);   // 4096 f32
  float* ksum    = Kmat + 4096;                     // 64 f32
  float* stats   = ksum + 64;                       // 48 f32
  float* coef    = stats + 48;                      // 48 f32
  float* Ggram   = coef + 48;                       // 12*4096 f32

  hipMemsetAsync(stats, 0, 48*sizeof(float), stream);
  hipMemsetAsync(Ggram, 0, 12*4096*sizeof(float), stream);

  dim3 tb(32, 8);
  k_transpose_cvt<<<dim3(1536/32, 768/32), tb, 0, stream>>>(W_qv,   W_qvT,   768, 1536);
  k_transpose_cvt<<<dim3(768/32,  768/32), tb, 0, stream>>>(W_proj, W_projT, 768, 768);
  k_cvt<<<4704, 256, 0, stream>>>(x, x_bf16);
  k_kprep<<<4, 256, 0, stream>>>(k_ext, Kmat, ksum);
  k_gemm<0><<<98*12, 256, 0, stream>>>(x_bf16, W_qvT, q_buf, v_buf, nullptr, nullptr, ksum, stats);
  k_gram<<<384, 256, 0, stream>>>(q_buf, Ggram);
  k_sfin<<<12, 256, 0, stream>>>(Ggram, Kmat, stats, bn_gamma, bn_beta, coef);
  k_attn<<<768, 256, 0, stream>>>(q_buf, v_buf, k_ext, attn_bias, coef, O_buf);
  k_gemm<1><<<98*6, 256, 0, stream>>>(O_buf, W_projT, nullptr, nullptr, out, b_proj, nullptr, nullptr);
}

// Round 9
// 194.583 us; speedup vs baseline: 1.4801x; 1.4801x over previous
//
#include <hip/hip_runtime.h>
#include <hip/hip_bf16.h>

typedef __bf16 b16;
typedef __bf16 b16x4 __attribute__((ext_vector_type(4)));
typedef __bf16 b16x8 __attribute__((ext_vector_type(8)));
typedef float  f32x4 __attribute__((ext_vector_type(4)));

#define B_   64
#define N_   196
#define C_   768
#define H_   12
#define HD_  64
#define TOK  (B_*N_)      // 12544
#define SCALE 0.125f

// async global->LDS, 16B per lane, wave-uniform LDS base
__device__ __forceinline__ void gl_lds16(const void* g, void* l){
  __builtin_amdgcn_global_load_lds((const __attribute__((address_space(1))) void*)g,
                                   (__attribute__((address_space(3))) void*)l, 16, 0, 0);
}

// ---------------------------------------------------------------- transpose+cvt
__global__ __launch_bounds__(256) void k_transpose_cvt(const float* __restrict__ in,
                                                       b16* __restrict__ out, int R, int C){
  __shared__ b16 tile[32][33];
  int tx = threadIdx.x, ty = threadIdx.y;
  int bx = blockIdx.x, by = blockIdx.y;
  int c = bx*32 + tx;
  #pragma unroll
  for (int i = 0; i < 32; i += 8){
    int r = by*32 + ty + i;
    tile[ty+i][tx] = (b16)in[(long)r*C + c];
  }
  __syncthreads();
  int rr = by*32 + tx;
  #pragma unroll
  for (int i = 0; i < 32; i += 8){
    int cc = bx*32 + ty + i;
    out[(long)cc*R + rr] = tile[tx][ty+i];
  }
}

// ---------------------------------------------------------------- x f32 -> bf16
__global__ __launch_bounds__(256) void k_cvt(const float* __restrict__ in, b16* __restrict__ out){
  long i = ((long)blockIdx.x*256 + threadIdx.x)*8;
  const float4* s = (const float4*)(in + i);
  float4 f0 = s[0], f1 = s[1];
  b16x8 v; v[0]=(b16)f0.x; v[1]=(b16)f0.y; v[2]=(b16)f0.z; v[3]=(b16)f0.w;
           v[4]=(b16)f1.x; v[5]=(b16)f1.y; v[6]=(b16)f1.z; v[7]=(b16)f1.w;
  *(b16x8*)(out + i) = v;
}

// ---------------------------------------------------------------- K = k^T k, ksum (4 blocks)
__global__ __launch_bounds__(256) void k_kprep(const float* __restrict__ k_ext,
                                               float* __restrict__ Kmat, float* __restrict__ ksum){
  __shared__ float ks[N_][HD_];
  int tid = threadIdx.x, blk = blockIdx.x;       // blk 0..3
  for (int i = tid; i < N_*HD_; i += 256) ks[i/HD_][i%HD_] = k_ext[i];
  __syncthreads();
  int i = tid >> 2;
  int j0 = blk*16 + (tid & 3)*4;
  float a0=0.f, a1=0.f, a2=0.f, a3=0.f;
  for (int p = 0; p < N_; ++p){
    float ki = ks[p][i];
    float4 kv = *(const float4*)&ks[p][j0];
    a0 += ki*kv.x; a1 += ki*kv.y; a2 += ki*kv.z; a3 += ki*kv.w;
  }
  Kmat[i*64+j0+0]=a0; Kmat[i*64+j0+1]=a1; Kmat[i*64+j0+2]=a2; Kmat[i*64+j0+3]=a3;
  if (blk == 0 && tid < 64){
    float s = 0.f;
    for (int p = 0; p < N_; ++p) s += ks[p][tid];
    ksum[tid] = s;
  }
}

// ---------------------------------------------------------------- tiled bf16 MFMA GEMM
// 256x256 tile, BK=32, 512 thr (8 waves, 2Mx4N), double-buffered LDS (64 KiB),
// round-5 counted-vmcnt schedule (depth-2 prefetch, vmcnt(4), 2 barriers/K-step),
// both-sides swizzle (verified conflicts=0), swapped-operand MFMA -> vectorized epilogue.
// Per block-K-step: 256 MFMA (4x the 128-tile version) against the same barrier cost.
// MODE0: q/v bf16 [b,n,h,d] rows + fused BN stats; MODE1: f32 out + bias
template<int MODE>
__global__ __launch_bounds__(512, 2) void k_gemm(const b16* __restrict__ A,
                                                 const b16* __restrict__ BT,
                                                 b16* __restrict__ qout, b16* __restrict__ vout,
                                                 float* __restrict__ fout, const float* __restrict__ bias,
                                                 const float* __restrict__ ksum, float* __restrict__ stats){
  const int NT  = (MODE == 0) ? 6 : 3;
  const int NWG = 49*NT;
  // bijective XCD swizzle (m204)
  int orig = blockIdx.x;
  int q8 = NWG >> 3, r8 = NWG & 7;
  int xcd = orig & 7, loc = orig >> 3;
  int bid = (xcd < r8 ? xcd*(q8+1) : r8*(q8+1) + (xcd-r8)*q8) + loc;
  int rt = bid / NT, ct = bid % NT;
  int brow = rt*256, bcol = ct*256;

  __shared__ char smc[2*32768];        // [buf][A 16K | B 16K]
  int tid = threadIdx.x, lane = tid & 63, w = tid >> 6;
  int wr = w >> 2, wc = w & 3;

  // staging: wave w covers rows [s*128 + w*16, +16), lane l -> row +(l>>2), group gsrc
  int gsrc = (lane & 3) ^ ((lane >> 3) & 3);
  const b16* gA = A  + (long)(brow + w*16 + (lane>>2))*768 + gsrc*8;
  const b16* gB = BT + (long)(bcol + w*16 + (lane>>2))*768 + gsrc*8;

#define STAGE(cur, t) do{ \
    char* ba = smc + (cur)*32768; \
    gl_lds16(gA + (long)(t)*32,           ba + (w*16)*64); \
    gl_lds16(gA + (long)(t)*32 + 128*768, ba + (128 + w*16)*64); \
    gl_lds16(gB + (long)(t)*32,           ba + 16384 + (w*16)*64); \
    gl_lds16(gB + (long)(t)*32 + 128*768, ba + 16384 + (128 + w*16)*64); \
  } while(0)

#define COMPUTE(cur) do{ \
    const char* ba = smc + (cur)*32768; \
    const char* bb = ba + 16384; \
    b16x8 af[8], bf[4]; \
    _Pragma("unroll") \
    for (int m = 0; m < 8; ++m){ \
      int row = wr*128 + m*16 + (lane & 15); \
      af[m] = *(const b16x8*)(ba + row*64 + (((lane>>4) ^ ((row>>1)&3))<<4)); \
    } \
    _Pragma("unroll") \
    for (int n = 0; n < 4; ++n){ \
      int row = wc*64 + n*16 + (lane & 15); \
      bf[n] = *(const b16x8*)(bb + row*64 + (((lane>>4) ^ ((row>>1)&3))<<4)); \
    } \
    _Pragma("unroll") \
    for (int m = 0; m < 8; ++m) \
      _Pragma("unroll") \
      for (int n = 0; n < 4; ++n) \
        acc[m][n] = __builtin_amdgcn_mfma_f32_16x16x32_bf16(bf[n], af[m], acc[m][n], 0, 0, 0); \
  } while(0)

  f32x4 acc[8][4];
  #pragma unroll
  for (int m = 0; m < 8; ++m)
    #pragma unroll
    for (int n = 0; n < 4; ++n) acc[m][n] = (f32x4){0.f,0.f,0.f,0.f};

  // prologue: tiles 0 and 1 in flight (4 loads each)
  STAGE(0, 0);
  STAGE(1, 1);

  #pragma unroll 1
  for (int kt = 0; kt < 23; ++kt){
    int cur = kt & 1;
    asm volatile("s_waitcnt vmcnt(4)" ::: "memory");   // tile kt landed; kt+1 in flight
    __builtin_amdgcn_s_barrier();
    asm volatile("" ::: "memory");
    COMPUTE(cur);
    asm volatile("s_waitcnt lgkmcnt(0)" ::: "memory"); // all ds_reads of buf cur retired
    __builtin_amdgcn_s_barrier();
    asm volatile("" ::: "memory");
    if (kt < 22) STAGE(cur, kt+2);                      // overwrite the buffer just read
  }
  asm volatile("s_waitcnt vmcnt(0)" ::: "memory");
  __builtin_amdgcn_s_barrier();
  asm volatile("" ::: "memory");
  COMPUTE(1);
#undef COMPUTE
#undef STAGE

  // epilogue: row = brow + wr*128 + m*16 + (lane&15); col = bcol + wc*64 + n*16 + (lane>>4)*4 + j
  if constexpr (MODE == 0){
    int hidx = ct*4 + wc;                 // 64-col group index in [0,24)
    bool isV = (hidx >= 12);
    b16* dst = isV ? vout : qout;
    int cb0 = bcol + wc*64 - (isV ? 768 : 0);
    #pragma unroll
    for (int m = 0; m < 8; ++m){
      int r2 = brow + wr*128 + m*16 + (lane & 15);
      #pragma unroll
      for (int n = 0; n < 4; ++n){
        int cc = cb0 + n*16 + ((lane>>4)<<2);
        b16x4 pv;
        #pragma unroll
        for (int j = 0; j < 4; ++j) pv[j] = (b16)acc[m][n][j];
        *(b16x4*)(dst + (long)r2*768 + cc) = pv;
      }
    }
    // fused BN stats (wave owns exactly ONE head)
    {
      float a_acc = 0.f, b_acc = 0.f;
      #pragma unroll
      for (int n = 0; n < 4; ++n)
        #pragma unroll
        for (int j = 0; j < 4; ++j){
          int d = n*16 + ((lane>>4)<<2) + j;        // col within head
          float s = 0.f, s2 = 0.f;
          #pragma unroll
          for (int m = 0; m < 8; ++m){
            float v = acc[m][n][j];
            s += v; s2 += v*v;
          }
          if (isV){ a_acc += s; b_acc += s2; }
          else      a_acc += s * ksum[d];
        }
      #pragma unroll
      for (int off = 1; off < 64; off <<= 1){
        a_acc += __shfl_xor(a_acc, off, 64);
        b_acc += __shfl_xor(b_acc, off, 64);
      }
      if (lane == 0){
        if (isV){
          atomicAdd(&stats[24 + (hidx-12)], a_acc);
          atomicAdd(&stats[36 + (hidx-12)], b_acc);
        } else {
          atomicAdd(&stats[hidx], a_acc);
        }
      }
    }
  } else {
    #pragma unroll
    for (int m = 0; m < 8; ++m){
      int r2 = brow + wr*128 + m*16 + (lane & 15);
      #pragma unroll
      for (int n = 0; n < 4; ++n){
        int cc = bcol + wc*64 + n*16 + ((lane>>4)<<2);
        f32x4 bv = *(const f32x4*)(bias + cc);
        f32x4 o;
        #pragma unroll
        for (int j = 0; j < 4; ++j) o[j] = acc[m][n][j] + bv[j];
        *(f32x4*)(fout + (long)r2*768 + cc) = o;
      }
    }
  }
}

// ---------------------------------------------------------------- per-head Gram G = sum_t q q^T (MFMA)
// q layout [b,n,h,d]: row stride 768
__global__ __launch_bounds__(256) void k_gram(const b16* __restrict__ qb, float* __restrict__ G){
  __shared__ b16 qT[64*232];          // [d][t] stride 232
  int tid = threadIdx.x, lane = tid & 63, w = tid >> 6;
  int h = blockIdx.x % 12, bg = blockIdx.x / 12;   // bg 0..31
  f32x4 acc[4];
  #pragma unroll
  for (int n = 0; n < 4; ++n) acc[n] = (f32x4){0.f,0.f,0.f,0.f};
  #pragma unroll 1
  for (int r = 0; r < 2; ++r){
    int b = bg*2 + r;
    const b16* src = qb + (long)(b*196)*768 + h*64;
    int d = lane;
    for (int p0 = w*8; p0 < 224; p0 += 32){
      b16x8 w8;
      #pragma unroll
      for (int j = 0; j < 8; ++j){
        int p = p0 + j;
        w8[j] = (p < 196) ? src[(long)p*768 + d] : (b16)0.f;
      }
      *(b16x8*)(qT + d*232 + p0) = w8;
    }
    __syncthreads();
    #pragma unroll
    for (int ks = 0; ks < 7; ++ks){
      int t0 = ks*32;
      b16x8 af = *(const b16x8*)(qT + (16*w + (lane&15))*232 + t0 + ((lane>>4)<<3));
      #pragma unroll
      for (int n = 0; n < 4; ++n){
        b16x8 bf = *(const b16x8*)(qT + (16*n + (lane&15))*232 + t0 + ((lane>>4)<<3));
        acc[n] = __builtin_amdgcn_mfma_f32_16x16x32_bf16(af, bf, acc[n], 0, 0, 0);
      }
    }
    __syncthreads();
  }
  float* Gh = G + h*4096;
  #pragma unroll
  for (int n = 0; n < 4; ++n)
    #pragma unroll
    for (int j = 0; j < 4; ++j){
      int i  = 16*w + ((lane>>4)<<2) + j;
      int jj = 16*n + (lane&15);
      atomicAdd(&Gh[i*64 + jj], acc[n][j]);
    }
}

// ---------------------------------------------------------------- S2 = <G,K>, finalize coefs
__global__ __launch_bounds__(256) void k_sfin(const float* __restrict__ G, const float* __restrict__ Kmat,
                                              const float* __restrict__ stats, const float* __restrict__ gamma,
                                              const float* __restrict__ beta, float* __restrict__ coef){
  int h = blockIdx.x, tid = threadIdx.x;
  const float* Gh = G + h*4096;
  float s = 0.f;
  #pragma unroll
  for (int k = 0; k < 16; ++k) s += Gh[tid + k*256]*Kmat[tid + k*256];
  #pragma unroll
  for (int off = 1; off < 64; off <<= 1) s += __shfl_xor(s, off, 64);
  __shared__ float red[4];
  if ((tid & 63) == 0) red[tid>>6] = s;
  __syncthreads();
  if (tid == 0){
    float S2 = red[0]+red[1]+red[2]+red[3];
    const float cntS = 2458624.f, cntV = 802816.f;
    float S1 = stats[h], VS = stats[24+h], VS2 = stats[36+h];
    float ms = S1/cntS;
    float vars = S2/cntS - ms*ms;
    float alpha = gamma[h]*SCALE*rsqrtf(vars + 1e-5f);
    float mv = VS/cntV;
    float varv = VS2/cntV - mv*mv;
    float a = gamma[h]*rsqrtf(varv + 1e-5f);
    coef[h*4+0] = alpha;
    coef[h*4+1] = a;
    coef[h*4+2] = beta[h] - a*mv;
  }
}

// ---------------------------------------------------------------- fused attention per (b,h)
// q/v layout [b,n,h,d]: row stride 768 elements (1536 B), head offset h*64
__global__ __launch_bounds__(256, 2) void k_attn(const b16* __restrict__ qb, const b16* __restrict__ vb,
                                                 const float* __restrict__ k_ext,
                                                 const float* __restrict__ attn_bias,
                                                 const float* __restrict__ coef,
                                                 b16* __restrict__ Ob){
  __shared__ b16 ksh[196*64];
  __shared__ b16 vsh[64*216];
  __shared__ b16 psh[4][16*200];
  __shared__ float bsh[196];

  int tid = threadIdx.x, lane = tid & 63, wid = tid >> 6;
  int bh = blockIdx.x;
  int h = bh % 12, b = bh / 12;
  const b16* qt = qb + (long)(b*196)*768 + h*64;
  const b16* vt = vb + (long)(b*196)*768 + h*64;
  float alpha = coef[h*4+0], av = coef[h*4+1], cv = coef[h*4+2];

  for (int c = tid; c < 196*8; c += 256){
    int p = c >> 3, g = c & 7;
    const float4* src = (const float4*)(k_ext + p*64 + g*8);
    float4 f0 = src[0], f1 = src[1];
    b16x8 v; v[0]=(b16)f0.x; v[1]=(b16)f0.y; v[2]=(b16)f0.z; v[3]=(b16)f0.w;
             v[4]=(b16)f1.x; v[5]=(b16)f1.y; v[6]=(b16)f1.z; v[7]=(b16)f1.w;
    *(b16x8*)((char*)ksh + p*128 + ((g ^ (p&7))<<4)) = v;
  }
  for (int p = tid; p < 196; p += 256) bsh[p] = attn_bias[p]*SCALE;
  {
    int d = tid & 63;
    for (int p0 = (tid>>6)*8; p0 < 196; p0 += 32){
      b16x8 w;
      #pragma unroll
      for (int j = 0; j < 8; ++j){
        int p = p0 + j;
        w[j] = (p < 196) ? vt[(long)p*768 + d] : (b16)0.f;
      }
      *(b16x8*)((char*)vsh + d*432 + p0*2) = w;
    }
  }
  __syncthreads();

  for (int rt = wid; rt < 13; rt += 4){
    int n0 = rt*16;
    int qrow = n0 + (lane & 15); if (qrow > 195) qrow = 195;
    b16x8 a0 = *(const b16x8*)((const char*)qt + (long)qrow*1536 +      ((lane>>4)<<4));
    b16x8 a1 = *(const b16x8*)((const char*)qt + (long)qrow*1536 + 64 + ((lane>>4)<<4));

    f32x4 sc[13];
    #pragma unroll
    for (int ct = 0; ct < 13; ++ct){
      int p = ct*16 + (lane & 15); int pc = p > 195 ? 195 : p;
      b16x8 b0 = *(const b16x8*)((const char*)ksh + pc*128 + ((( (lane>>4))   ^ (pc&7))<<4));
      b16x8 b1 = *(const b16x8*)((const char*)ksh + pc*128 + (((4+(lane>>4))  ^ (pc&7))<<4));
      f32x4 z = {0.f,0.f,0.f,0.f};
      z = __builtin_amdgcn_mfma_f32_16x16x32_bf16(a0, b0, z, 0, 0, 0);
      z = __builtin_amdgcn_mfma_f32_16x16x32_bf16(a1, b1, z, 0, 0, 0);
      sc[ct] = z;
    }
    int pcol = lane & 15;
    float mx[4] = {-1e30f,-1e30f,-1e30f,-1e30f};
    #pragma unroll
    for (int ct = 0; ct < 13; ++ct){
      int p = ct*16 + pcol;
      bool valid = (p < 196);
      float badd = valid ? bsh[p < 196 ? p : 0] : 0.f;
      #pragma unroll
      for (int j = 0; j < 4; ++j){
        float lv = valid ? (sc[ct][j]*alpha + badd) : -1e30f;
        sc[ct][j] = lv;
        mx[j] = fmaxf(mx[j], lv);
      }
    }
    #pragma unroll
    for (int off = 1; off < 16; off <<= 1)
      #pragma unroll
      for (int j = 0; j < 4; ++j) mx[j] = fmaxf(mx[j], __shfl_xor(mx[j], off, 64));
    float sm[4] = {0.f,0.f,0.f,0.f};
    #pragma unroll
    for (int ct = 0; ct < 13; ++ct)
      #pragma unroll
      for (int j = 0; j < 4; ++j){
        float e = __expf(sc[ct][j] - mx[j]);
        sc[ct][j] = e; sm[j] += e;
      }
    #pragma unroll
    for (int off = 1; off < 16; off <<= 1)
      #pragma unroll
      for (int j = 0; j < 4; ++j) sm[j] += __shfl_xor(sm[j], off, 64);
    float rs[4];
    #pragma unroll
    for (int j = 0; j < 4; ++j) rs[j] = 1.f/sm[j];

    b16* pw = psh[wid];
    #pragma unroll
    for (int ct = 0; ct < 12; ++ct){
      int p = ct*16 + pcol;
      #pragma unroll
      for (int j = 0; j < 4; ++j){
        int r = ((lane>>4)<<2) + j;
        pw[r*200 + p] = (b16)(sc[ct][j]*rs[j]);
      }
    }
    float pt12[4];
    #pragma unroll
    for (int j = 0; j < 4; ++j) pt12[j] = sc[12][j]*rs[j];

    __asm__ volatile("s_waitcnt lgkmcnt(0)" ::: "memory");
    __builtin_amdgcn_sched_barrier(0);

    f32x4 o[4];
    #pragma unroll
    for (int dt = 0; dt < 4; ++dt) o[dt] = (f32x4){0.f,0.f,0.f,0.f};
    #pragma unroll
    for (int pt = 0; pt < 6; ++pt){
      b16x8 pa = *(const b16x8*)((const char*)pw + (lane&15)*400 + pt*64 + ((lane>>4)<<4));
      #pragma unroll
      for (int dt = 0; dt < 4; ++dt){
        b16x8 vf = *(const b16x8*)((const char*)vsh + (dt*16 + (lane&15))*432 + pt*64 + ((lane>>4)<<4));
        o[dt] = __builtin_amdgcn_mfma_f32_16x16x32_bf16(pa, vf, o[dt], 0, 0, 0);
      }
    }
    #pragma unroll
    for (int e = 0; e < 4; ++e){
      float pe[4];
      #pragma unroll
      for (int j = 0; j < 4; ++j) pe[j] = __shfl(pt12[j], (lane & 48) + e, 64);
      #pragma unroll
      for (int dt = 0; dt < 4; ++dt){
        b16 vv = *((const b16*)((const char*)vsh + (dt*16 + (lane&15))*432 + (192+e)*2));
        float vvf = (float)vv;
        #pragma unroll
        for (int j = 0; j < 4; ++j) o[dt][j] += pe[j]*vvf;
      }
    }
    #pragma unroll
    for (int dt = 0; dt < 4; ++dt)
      #pragma unroll
      for (int j = 0; j < 4; ++j){
        int n = n0 + ((lane>>4)<<2) + j;
        if (n < 196){
          long idx = ((long)(b*196 + n))*768 + h*64 + dt*16 + (lane&15);
          Ob[idx] = (b16)(av*o[dt][j] + cv);
        }
      }
  }
}

// ---------------------------------------------------------------- launch
extern "C" void kernel_launch(void* const* d_in, const int* in_sizes, int n_in,
                              void* d_out, int out_size, void* d_ws, size_t ws_size,
                              hipStream_t stream){
  const float* x         = (const float*)d_in[0];
  const float* W_qv      = (const float*)d_in[1];
  const float* k_ext     = (const float*)d_in[2];
  const float* attn_bias = (const float*)d_in[3];
  const float* bn_gamma  = (const float*)d_in[4];
  const float* bn_beta   = (const float*)d_in[5];
  const float* W_proj    = (const float*)d_in[6];
  const float* b_proj    = (const float*)d_in[7];
  float* out = (float*)d_out;

  char* ws = (char*)d_ws;
  const long SZ = 19267584;              // 9,633,792 bf16
  b16*   q_buf   = (b16*)(ws);
  b16*   v_buf   = (b16*)(ws + SZ);
  b16*   O_buf   = (b16*)(ws + 2*SZ);    // doubles as x_bf16 before k_attn
  b16*   x_bf16  = (b16*)(ws + 2*SZ);
  b16*   W_qvT   = (b16*)(ws + 3*SZ);
  b16*   W_projT = (b16*)(ws + 3*SZ + 2359296);
  float* Kmat    = (float*)(ws + 3*SZ + 3538944);   // 4096 f32
  float* ksum    = Kmat + 4096;                     // 64 f32
  float* stats   = ksum + 64;                       // 48 f32
  float* coef    = stats + 48;                      // 48 f32
  float* Ggram   = coef + 48;                       // 12*4096 f32

  hipMemsetAsync(stats, 0, 48*sizeof(float), stream);
  hipMemsetAsync(Ggram, 0, 12*4096*sizeof(float), stream);

  dim3 tb(32, 8);
  k_transpose_cvt<<<dim3(1536/32, 768/32), tb, 0, stream>>>(W_qv,   W_qvT,   768, 1536);
  k_transpose_cvt<<<dim3(768/32,  768/32), tb, 0, stream>>>(W_proj, W_projT, 768, 768);
  k_cvt<<<4704, 256, 0, stream>>>(x, x_bf16);
  k_kprep<<<4, 256, 0, stream>>>(k_ext, Kmat, ksum);
  k_gemm<0><<<49*6, 512, 0, stream>>>(x_bf16, W_qvT, q_buf, v_buf, nullptr, nullptr, ksum, stats);
  k_gram<<<384, 256, 0, stream>>>(q_buf, Ggram);
  k_sfin<<<12, 256, 0, stream>>>(Ggram, Kmat, stats, bn_gamma, bn_beta, coef);
  k_attn<<<768, 256, 0, stream>>>(q_buf, v_buf, k_ext, attn_bias, coef, O_buf);
  k_gemm<1><<<49*3, 512, 0, stream>>>(O_buf, W_projT, nullptr, nullptr, out, b_proj, nullptr, nullptr);
}